// Round 1
// baseline (522.707 us; speedup 1.0000x reference)
//
#include <hip/hip_runtime.h>
#include <math.h>

#define D 128
#define HD 256
#define N_ENT 100000
#define NBATCH 64
#define NTOT (N_ENT + NBATCH)   // 100064
#define RCOUNT 500
#define E_BASE 400000
#define ETOT (E_BASE + N_ENT)   // 500000
#define NEG 0.2f
#define SCAN_NB 391             // ceil(100000/256)

// ---------------- e_rel (501x256) + out_edge (500x128) ----------------
__global__ __launch_bounds__(256) void k_rel(
    const float* __restrict__ relations, const float* __restrict__ W_ea,
    const float* __restrict__ W_le, const float* __restrict__ b_le,
    float* __restrict__ e_rel, float* __restrict__ out_edge) {
  __shared__ float relu_p[HD];
  int r = blockIdx.x;
  int j = threadIdx.x;
  const float* w = W_ea + (size_t)j * D;
  float acc = 0.f;
  if (r < RCOUNT) {
    const float* rel = relations + (size_t)r * D;
    for (int k = 0; k < D; k += 4) {
      float4 a = *(const float4*)(rel + k);
      float4 b = *(const float4*)(w + k);
      acc += a.x * b.x + a.y * b.y + a.z * b.z + a.w * b.w;
    }
  } else {  // r == RCOUNT: the all-ones rel_feat row -> row sums of W_ea
    for (int k = 0; k < D; k += 4) {
      float4 b = *(const float4*)(w + k);
      acc += b.x + b.y + b.z + b.w;
    }
  }
  e_rel[(size_t)r * HD + j] = acc;
  if (r < RCOUNT) {
    relu_p[j] = acc > 0.f ? acc : 0.f;
    __syncthreads();
    if (j < D) {
      const float* wl = W_le + (size_t)j * HD;
      float o = b_le[j];
      for (int k = 0; k < HD; k += 4) {
        float4 p4 = *(const float4*)(relu_p + k);
        float4 w4 = *(const float4*)(wl + k);
        o += p4.x * w4.x + p4.y * w4.y + p4.z * w4.z + p4.w * w4.w;
      }
      out_edge[(size_t)r * D + j] = o;
    }
  }
}

// ---------------- x_l / x_r GEMM: node(100064x128) @ [W_l|W_r]^T ----------------
#define GS 132  // padded LDS row stride (floats); keeps 16B alignment, breaks bank conflicts

__global__ __launch_bounds__(256) void k_gemm(
    const float* __restrict__ entities, const float* __restrict__ queries,
    const float* __restrict__ W_l, const float* __restrict__ b_l,
    const float* __restrict__ W_r, const float* __restrict__ b_r,
    float* __restrict__ x_l, float* __restrict__ x_r) {
  __shared__ float As[64 * GS];
  __shared__ float Bs[64 * GS];
  int rb = blockIdx.x, cb = blockIdx.y;  // row tile, virtual-col tile (8 tiles of 64 over [x_l|x_r])
  int tid = threadIdx.x;
  {
    int rr = tid >> 2;
    int part = (tid & 3) * 32;
    int row = rb * 64 + rr;
    const float* sp;
    if (row < N_ENT) sp = entities + (size_t)row * D;
    else if (row < NTOT) sp = queries + (size_t)(row - N_ENT) * D;
    else sp = entities;  // dummy, stores guarded later
    int c = cb * 64 + rr;
    const float* wp = (c < HD) ? (W_l + (size_t)c * D) : (W_r + (size_t)(c - HD) * D);
#pragma unroll
    for (int k = 0; k < 32; k += 4) {
      *(float4*)(&As[rr * GS + part + k]) = *(const float4*)(sp + part + k);
      *(float4*)(&Bs[rr * GS + part + k]) = *(const float4*)(wp + part + k);
    }
  }
  __syncthreads();
  int ty = tid >> 4, tx = tid & 15;
  float acc[4][4];
#pragma unroll
  for (int i = 0; i < 4; i++)
#pragma unroll
    for (int j = 0; j < 4; j++) acc[i][j] = 0.f;
  for (int k = 0; k < D; k += 4) {
    float4 a[4], b[4];
#pragma unroll
    for (int i = 0; i < 4; i++) a[i] = *(const float4*)(&As[(ty + 16 * i) * GS + k]);
#pragma unroll
    for (int j = 0; j < 4; j++) b[j] = *(const float4*)(&Bs[(tx + 16 * j) * GS + k]);
#pragma unroll
    for (int i = 0; i < 4; i++)
#pragma unroll
      for (int j = 0; j < 4; j++)
        acc[i][j] += a[i].x * b[j].x + a[i].y * b[j].y + a[i].z * b[j].z + a[i].w * b[j].w;
  }
  int cvirt = cb * 64 + tx;
  bool isL = cvirt < HD;
  const float* bv = isL ? b_l : b_r;
  float* dst = isL ? x_l : x_r;
  int cbase = isL ? cvirt : cvirt - HD;
  float bb[4];
#pragma unroll
  for (int j = 0; j < 4; j++) bb[j] = bv[cbase + 16 * j];
#pragma unroll
  for (int i = 0; i < 4; i++) {
    int row = rb * 64 + ty + 16 * i;
    if (row < NTOT) {
#pragma unroll
      for (int j = 0; j < 4; j++)
        dst[(size_t)row * HD + cbase + 16 * j] = acc[i][j] + bb[j];
    }
  }
}

// ---------------- counting sort of edges by target ----------------
__global__ void k_zero(int* __restrict__ counts) {
  int i = blockIdx.x * 256 + threadIdx.x;
  if (i < N_ENT) counts[i] = 0;
}

__global__ void k_hist(const int* __restrict__ edge_index, int* __restrict__ counts) {
  int e = blockIdx.x * 256 + threadIdx.x;
  if (e >= ETOT) return;
  int t = (e < E_BASE) ? edge_index[E_BASE + e] : (e - E_BASE);
  atomicAdd(counts + t, 1);
}

__global__ void k_scan1(const int* __restrict__ counts, int* __restrict__ bsum) {
  __shared__ int sdata[256];
  int i = blockIdx.x * 256 + threadIdx.x;
  sdata[threadIdx.x] = (i < N_ENT) ? counts[i] : 0;
  __syncthreads();
  for (int off = 128; off > 0; off >>= 1) {
    if (threadIdx.x < off) sdata[threadIdx.x] += sdata[threadIdx.x + off];
    __syncthreads();
  }
  if (threadIdx.x == 0) bsum[blockIdx.x] = sdata[0];
}

__global__ void k_scan2(const int* __restrict__ bsum, int* __restrict__ bpre) {
  __shared__ int s[512];
  int tid = threadIdx.x;
  s[tid] = (tid < SCAN_NB) ? bsum[tid] : 0;
  __syncthreads();
  for (int off = 1; off < 512; off <<= 1) {
    int y = (tid >= off) ? s[tid - off] : 0;
    __syncthreads();
    s[tid] += y;
    __syncthreads();
  }
  bpre[tid] = (tid == 0) ? 0 : s[tid - 1];
}

__global__ void k_scan3(const int* __restrict__ counts, const int* __restrict__ bpre,
                        int* __restrict__ offsets, int* __restrict__ cursor) {
  __shared__ int s[256];
  int tid = threadIdx.x;
  int i = blockIdx.x * 256 + tid;
  int v = (i < N_ENT) ? counts[i] : 0;
  s[tid] = v;
  __syncthreads();
  for (int off = 1; off < 256; off <<= 1) {
    int y = (tid >= off) ? s[tid - off] : 0;
    __syncthreads();
    s[tid] += y;
    __syncthreads();
  }
  int excl = bpre[blockIdx.x] + s[tid] - v;
  if (i <= N_ENT) offsets[i] = excl;   // i==N_ENT lands on total == ETOT
  if (i < N_ENT) cursor[i] = excl;
}

__global__ void k_scatter(const int* __restrict__ edge_index, const int* __restrict__ relation_index,
                          const int* __restrict__ batch, int* __restrict__ cursor,
                          unsigned int* __restrict__ sorted) {
  int e = blockIdx.x * 256 + threadIdx.x;
  if (e >= ETOT) return;
  int s, t, r;
  if (e < E_BASE) {
    s = edge_index[e];
    t = edge_index[E_BASE + e];
    r = relation_index[e];
  } else {
    int i = e - E_BASE;
    s = N_ENT + batch[i];  // query node source
    t = i;
    r = RCOUNT;            // the all-ones relation row
  }
  int pos = atomicAdd(cursor + t, 1);
  sorted[pos] = (unsigned)s | ((unsigned)r << 17);  // s<2^17, r<2^9
}

// ---------------- per-target online-softmax aggregate ----------------
// one wave per target; lane l owns elems [4l,4l+4) of the (h*D+d) 256-vector
__global__ __launch_bounds__(256) void k_edge(
    const float* __restrict__ x_l, const float* __restrict__ x_r,
    const float* __restrict__ e_rel, const int* __restrict__ offsets,
    const unsigned int* __restrict__ sorted, const float* __restrict__ att,
    const float* __restrict__ bias, float* __restrict__ out) {
  int wv = threadIdx.x >> 6;
  int lane = threadIdx.x & 63;
  int t = blockIdx.x * 4 + wv;  // grid is exactly N_ENT/4
  int elem = lane * 4;
  int d = elem & (D - 1);
  float4 xr = *(const float4*)(x_r + (size_t)t * HD + elem);
  float4 at = *(const float4*)(att + elem);
  int e0 = offsets[t], e1 = offsets[t + 1];
  float m = -INFINITY, denom = 0.f;
  float4 acc = make_float4(0.f, 0.f, 0.f, 0.f);
  for (int e = e0; e < e1; e++) {
    unsigned sr = sorted[e];
    int s = sr & 0x1FFFF;
    int r = sr >> 17;
    float4 xl = *(const float4*)(x_l + (size_t)s * HD + elem);
    float4 er = *(const float4*)(e_rel + (size_t)r * HD + elem);
    float zx = xl.x + xr.x + er.x; zx = zx > 0.f ? zx : NEG * zx;
    float zy = xl.y + xr.y + er.y; zy = zy > 0.f ? zy : NEG * zy;
    float zz = xl.z + xr.z + er.z; zz = zz > 0.f ? zz : NEG * zz;
    float zw = xl.w + xr.w + er.w; zw = zw > 0.f ? zw : NEG * zw;
    float p = zx * at.x + zy * at.y + zz * at.z + zw * at.w;
    // reduce within each 32-lane half (head 0 = lanes 0-31, head 1 = lanes 32-63)
    p += __shfl_xor(p, 1, 64);
    p += __shfl_xor(p, 2, 64);
    p += __shfl_xor(p, 4, 64);
    p += __shfl_xor(p, 8, 64);
    p += __shfl_xor(p, 16, 64);
    float mnew = fmaxf(m, p);
    float corr = __expf(m - mnew);  // first iter: exp(-inf)=0
    float w = __expf(p - mnew);
    denom = denom * corr + w;
    acc.x = acc.x * corr + w * xl.x;
    acc.y = acc.y * corr + w * xl.y;
    acc.z = acc.z * corr + w * xl.z;
    acc.w = acc.w * corr + w * xl.w;
    m = mnew;
  }
  float inv = 1.f / (denom + 1e-16f);
  acc.x *= inv; acc.y *= inv; acc.z *= inv; acc.w *= inv;
  // combine heads: partner lane l^32 holds same d, other head
  float ox = acc.x + __shfl_xor(acc.x, 32, 64);
  float oy = acc.y + __shfl_xor(acc.y, 32, 64);
  float oz = acc.z + __shfl_xor(acc.z, 32, 64);
  float ow = acc.w + __shfl_xor(acc.w, 32, 64);
  if (lane < 32) {
    float4 b4 = *(const float4*)(bias + d);
    *(float4*)(out + (size_t)t * D + d) =
        make_float4(ox * 0.5f + b4.x, oy * 0.5f + b4.y, oz * 0.5f + b4.z, ow * 0.5f + b4.w);
  }
}

extern "C" void kernel_launch(void* const* d_in, const int* in_sizes, int n_in,
                              void* d_out, int out_size, void* d_ws, size_t ws_size,
                              hipStream_t stream) {
  const float* queries = (const float*)d_in[0];
  const float* entities = (const float*)d_in[1];
  const int* edge_index = (const int*)d_in[2];
  const float* relations = (const float*)d_in[3];
  const int* relation_index = (const int*)d_in[4];
  const int* batch = (const int*)d_in[5];
  const float* W_l = (const float*)d_in[6];
  const float* b_l = (const float*)d_in[7];
  const float* W_r = (const float*)d_in[8];
  const float* b_r = (const float*)d_in[9];
  const float* W_ea = (const float*)d_in[10];
  const float* att = (const float*)d_in[11];
  const float* bias = (const float*)d_in[12];
  const float* W_le = (const float*)d_in[13];
  const float* b_le = (const float*)d_in[14];

  float* out_node = (float*)d_out;
  float* out_edge = out_node + (size_t)N_ENT * D;

  char* base = (char*)d_ws;
  size_t off = 0;
  auto take = [&](size_t nbytes) -> void* {
    void* p = base + off;
    off += (nbytes + 255) & ~(size_t)255;
    return p;
  };
  float* x_l = (float*)take((size_t)NTOT * HD * sizeof(float));           // 102.5 MB
  float* x_r = (float*)take((size_t)NTOT * HD * sizeof(float));           // 102.5 MB
  float* e_rel = (float*)take((size_t)(RCOUNT + 1) * HD * sizeof(float)); // 513 KB
  int* counts = (int*)take((size_t)N_ENT * sizeof(int));
  int* offsets = (int*)take((size_t)(N_ENT + 1) * sizeof(int));
  int* cursor = (int*)take((size_t)N_ENT * sizeof(int));
  int* bsum = (int*)take(512 * sizeof(int));
  int* bpre = (int*)take(512 * sizeof(int));
  unsigned int* sorted = (unsigned int*)take((size_t)ETOT * sizeof(unsigned int)); // 2 MB

  k_rel<<<dim3(RCOUNT + 1), dim3(256), 0, stream>>>(relations, W_ea, W_le, b_le, e_rel, out_edge);
  k_gemm<<<dim3((NTOT + 63) / 64, 8), dim3(256), 0, stream>>>(entities, queries, W_l, b_l, W_r, b_r, x_l, x_r);
  k_zero<<<dim3((N_ENT + 255) / 256), dim3(256), 0, stream>>>(counts);
  k_hist<<<dim3((ETOT + 255) / 256), dim3(256), 0, stream>>>(edge_index, counts);
  k_scan1<<<dim3(SCAN_NB), dim3(256), 0, stream>>>(counts, bsum);
  k_scan2<<<dim3(1), dim3(512), 0, stream>>>(bsum, bpre);
  k_scan3<<<dim3(SCAN_NB), dim3(256), 0, stream>>>(counts, bpre, offsets, cursor);
  k_scatter<<<dim3((ETOT + 255) / 256), dim3(256), 0, stream>>>(edge_index, relation_index, batch, cursor, sorted);
  k_edge<<<dim3(N_ENT / 4), dim3(256), 0, stream>>>(x_l, x_r, e_rel, offsets, sorted, att, bias, out_node);
}

// Round 2
// 396.257 us; speedup vs baseline: 1.3191x; 1.3191x over previous
//
#include <hip/hip_runtime.h>
#include <math.h>

#define D 128
#define HD 256
#define N_ENT 100000
#define NBATCH 64
#define NTOT (N_ENT + NBATCH)   // 100064
#define RCOUNT 500
#define E_BASE 400000
#define ETOT (E_BASE + N_ENT)   // 500000
#define NEG 0.2f
#define SCAN_NB 391             // ceil(100000/256)

typedef __attribute__((ext_vector_type(8))) short bf16x8;
typedef __attribute__((ext_vector_type(4))) float f32x4;

static __device__ __forceinline__ unsigned short f2bf(float f) {
  unsigned u = __builtin_bit_cast(unsigned, f);
  u += 0x7fffu + ((u >> 16) & 1u);   // RNE
  return (unsigned short)(u >> 16);
}
static __device__ __forceinline__ float bf2f(unsigned short h) {
  return __builtin_bit_cast(float, (unsigned)h << 16);
}

// ---------------- e_rel (501x256) + out_edge (500x128), fp32 ----------------
__global__ __launch_bounds__(256) void k_rel(
    const float* __restrict__ relations, const float* __restrict__ W_ea,
    const float* __restrict__ W_le, const float* __restrict__ b_le,
    float* __restrict__ e_rel, float* __restrict__ out_edge) {
  __shared__ float relu_p[HD];
  int r = blockIdx.x;
  int j = threadIdx.x;
  const float* w = W_ea + (size_t)j * D;
  float acc = 0.f;
  if (r < RCOUNT) {
    const float* rel = relations + (size_t)r * D;
    for (int k = 0; k < D; k += 4) {
      float4 a = *(const float4*)(rel + k);
      float4 b = *(const float4*)(w + k);
      acc += a.x * b.x + a.y * b.y + a.z * b.z + a.w * b.w;
    }
  } else {  // all-ones rel_feat row -> row sums of W_ea
    for (int k = 0; k < D; k += 4) {
      float4 b = *(const float4*)(w + k);
      acc += b.x + b.y + b.z + b.w;
    }
  }
  e_rel[(size_t)r * HD + j] = acc;
  if (r < RCOUNT) {
    relu_p[j] = acc > 0.f ? acc : 0.f;
    __syncthreads();
    if (j < D) {
      const float* wl = W_le + (size_t)j * HD;
      float o = b_le[j];
      for (int k = 0; k < HD; k += 4) {
        float4 p4 = *(const float4*)(relu_p + k);
        float4 w4 = *(const float4*)(wl + k);
        o += p4.x * w4.x + p4.y * w4.y + p4.z * w4.z + p4.w * w4.w;
      }
      out_edge[(size_t)r * D + j] = o;
    }
  }
}

// ---------------- MFMA GEMM: [x_l|x_r](100064x512) = node @ [W_l|W_r]^T, bf16 out ----------------
#define LDA 136  // LDS row stride in bf16 units (272 B = 17*16B: aligned, bank-step 4)

__global__ __launch_bounds__(256) void k_gemm_mfma(
    const float* __restrict__ entities, const float* __restrict__ queries,
    const float* __restrict__ W_l, const float* __restrict__ b_l,
    const float* __restrict__ W_r, const float* __restrict__ b_r,
    unsigned short* __restrict__ x_l, unsigned short* __restrict__ x_r) {
  __shared__ unsigned short As[128 * LDA];
  __shared__ unsigned short Bs[128 * LDA];
  int rb = blockIdx.x, cb = blockIdx.y;  // 128-row tile, 128-virtual-col tile (of 512)
  int tid = threadIdx.x;

  // stage A (node rows, fp32 -> bf16) and B (W rows)
  {
    int rr = tid >> 1;                 // 0..127
    int part = (tid & 1) * 64;         // half of K
    int row = rb * 128 + rr;
    const float* sp;
    if (row < N_ENT) sp = entities + (size_t)row * D;
    else if (row < NTOT) sp = queries + (size_t)(row - N_ENT) * D;
    else sp = entities;  // dummy; stores guarded
    int c = cb * 128 + rr;             // virtual col 0..511
    const float* wp = (c < HD) ? (W_l + (size_t)c * D) : (W_r + (size_t)(c - HD) * D);
#pragma unroll
    for (int k = 0; k < 64; k += 8) {
      float4 a0 = *(const float4*)(sp + part + k);
      float4 a1 = *(const float4*)(sp + part + k + 4);
      ushort4 pa0 = make_ushort4(f2bf(a0.x), f2bf(a0.y), f2bf(a0.z), f2bf(a0.w));
      ushort4 pa1 = make_ushort4(f2bf(a1.x), f2bf(a1.y), f2bf(a1.z), f2bf(a1.w));
      *(ushort4*)(&As[rr * LDA + part + k]) = pa0;
      *(ushort4*)(&As[rr * LDA + part + k + 4]) = pa1;
      float4 b0 = *(const float4*)(wp + part + k);
      float4 b1 = *(const float4*)(wp + part + k + 4);
      ushort4 pb0 = make_ushort4(f2bf(b0.x), f2bf(b0.y), f2bf(b0.z), f2bf(b0.w));
      ushort4 pb1 = make_ushort4(f2bf(b1.x), f2bf(b1.y), f2bf(b1.z), f2bf(b1.w));
      *(ushort4*)(&Bs[rr * LDA + part + k]) = pb0;
      *(ushort4*)(&Bs[rr * LDA + part + k + 4]) = pb1;
    }
  }
  __syncthreads();

  int w = tid >> 6, lane = tid & 63;
  int wr = w >> 1, wc = w & 1;          // 2x2 wave grid; wave tile 64x64
  int m = lane & 15, k8 = (lane >> 4) * 8;

  f32x4 acc[4][4];
#pragma unroll
  for (int i = 0; i < 4; i++)
#pragma unroll
    for (int j = 0; j < 4; j++) acc[i][j] = (f32x4){0.f, 0.f, 0.f, 0.f};

#pragma unroll
  for (int ks = 0; ks < 128; ks += 32) {
    bf16x8 af[4], bfr[4];
#pragma unroll
    for (int i = 0; i < 4; i++)
      af[i] = *(const bf16x8*)(&As[(wr * 64 + i * 16 + m) * LDA + ks + k8]);
#pragma unroll
    for (int j = 0; j < 4; j++)
      bfr[j] = *(const bf16x8*)(&Bs[(wc * 64 + j * 16 + m) * LDA + ks + k8]);
#pragma unroll
    for (int i = 0; i < 4; i++)
#pragma unroll
      for (int j = 0; j < 4; j++)
        acc[i][j] = __builtin_amdgcn_mfma_f32_16x16x32_bf16(af[i], bfr[j], acc[i][j], 0, 0, 0);
  }

  // epilogue: C/D layout col=lane&15, row=(lane>>4)*4+reg
  int colbase = cb * 128 + wc * 64;     // wave tile is entirely in x_l or x_r half? 64-aligned vs 256 split: yes, uniform
#pragma unroll
  for (int j = 0; j < 4; j++) {
    int cv = colbase + j * 16 + (lane & 15);
    bool isL = cv < HD;
    unsigned short* dst = isL ? x_l : x_r;
    int c = isL ? cv : cv - HD;
    float bv = isL ? b_l[c] : b_r[c];
#pragma unroll
    for (int i = 0; i < 4; i++) {
      int row0 = rb * 128 + wr * 64 + i * 16 + (lane >> 4) * 4;
#pragma unroll
      for (int r = 0; r < 4; r++) {
        int row = row0 + r;
        if (row < NTOT) dst[(size_t)row * HD + c] = f2bf(acc[i][j][r] + bv);
      }
    }
  }
}

// ---------------- counting sort of edges by target ----------------
__global__ void k_zero(int* __restrict__ counts) {
  int i = blockIdx.x * 256 + threadIdx.x;
  if (i < N_ENT) counts[i] = 0;
}

__global__ void k_hist(const int* __restrict__ edge_index, int* __restrict__ counts) {
  int e = blockIdx.x * 256 + threadIdx.x;
  if (e >= ETOT) return;
  int t = (e < E_BASE) ? edge_index[E_BASE + e] : (e - E_BASE);
  atomicAdd(counts + t, 1);
}

__global__ void k_scan1(const int* __restrict__ counts, int* __restrict__ bsum) {
  __shared__ int sdata[256];
  int i = blockIdx.x * 256 + threadIdx.x;
  sdata[threadIdx.x] = (i < N_ENT) ? counts[i] : 0;
  __syncthreads();
  for (int off = 128; off > 0; off >>= 1) {
    if (threadIdx.x < off) sdata[threadIdx.x] += sdata[threadIdx.x + off];
    __syncthreads();
  }
  if (threadIdx.x == 0) bsum[blockIdx.x] = sdata[0];
}

__global__ void k_scan2(const int* __restrict__ bsum, int* __restrict__ bpre) {
  __shared__ int s[512];
  int tid = threadIdx.x;
  s[tid] = (tid < SCAN_NB) ? bsum[tid] : 0;
  __syncthreads();
  for (int off = 1; off < 512; off <<= 1) {
    int y = (tid >= off) ? s[tid - off] : 0;
    __syncthreads();
    s[tid] += y;
    __syncthreads();
  }
  bpre[tid] = (tid == 0) ? 0 : s[tid - 1];
}

__global__ void k_scan3(const int* __restrict__ counts, const int* __restrict__ bpre,
                        int* __restrict__ offsets, int* __restrict__ cursor) {
  __shared__ int s[256];
  int tid = threadIdx.x;
  int i = blockIdx.x * 256 + tid;
  int v = (i < N_ENT) ? counts[i] : 0;
  s[tid] = v;
  __syncthreads();
  for (int off = 1; off < 256; off <<= 1) {
    int y = (tid >= off) ? s[tid - off] : 0;
    __syncthreads();
    s[tid] += y;
    __syncthreads();
  }
  int excl = bpre[blockIdx.x] + s[tid] - v;
  if (i <= N_ENT) offsets[i] = excl;   // i==N_ENT -> total == ETOT
  if (i < N_ENT) cursor[i] = excl;
}

__global__ void k_scatter(const int* __restrict__ edge_index, const int* __restrict__ relation_index,
                          const int* __restrict__ batch, int* __restrict__ cursor,
                          unsigned int* __restrict__ sorted) {
  int e = blockIdx.x * 256 + threadIdx.x;
  if (e >= ETOT) return;
  int s, t, r;
  if (e < E_BASE) {
    s = edge_index[e];
    t = edge_index[E_BASE + e];
    r = relation_index[e];
  } else {
    int i = e - E_BASE;
    s = N_ENT + batch[i];
    t = i;
    r = RCOUNT;
  }
  int pos = atomicAdd(cursor + t, 1);
  sorted[pos] = (unsigned)s | ((unsigned)r << 17);  // s<2^17, r<2^9
}

// ---------------- per-target online-softmax aggregate (bf16 gathers) ----------------
__global__ __launch_bounds__(256) void k_edge(
    const unsigned short* __restrict__ x_l, const unsigned short* __restrict__ x_r,
    const float* __restrict__ e_rel, const int* __restrict__ offsets,
    const unsigned int* __restrict__ sorted, const float* __restrict__ att,
    const float* __restrict__ bias, float* __restrict__ out) {
  int wv = threadIdx.x >> 6;
  int lane = threadIdx.x & 63;
  int t = blockIdx.x * 4 + wv;  // grid is exactly N_ENT/4
  int elem = lane * 4;
  int d = elem & (D - 1);
  ushort4 xr4 = *(const ushort4*)(x_r + (size_t)t * HD + elem);
  float xrx = bf2f(xr4.x), xry = bf2f(xr4.y), xrz = bf2f(xr4.z), xrw = bf2f(xr4.w);
  float4 at = *(const float4*)(att + elem);
  int e0 = offsets[t], e1 = offsets[t + 1];
  float m = -INFINITY, denom = 0.f;
  float4 acc = make_float4(0.f, 0.f, 0.f, 0.f);
  for (int e = e0; e < e1; e++) {
    unsigned sr = sorted[e];
    int s = sr & 0x1FFFF;
    int r = sr >> 17;
    ushort4 xl4 = *(const ushort4*)(x_l + (size_t)s * HD + elem);
    float4 er = *(const float4*)(e_rel + (size_t)r * HD + elem);
    float xlx = bf2f(xl4.x), xly = bf2f(xl4.y), xlz = bf2f(xl4.z), xlw = bf2f(xl4.w);
    float zx = xlx + xrx + er.x; zx = zx > 0.f ? zx : NEG * zx;
    float zy = xly + xry + er.y; zy = zy > 0.f ? zy : NEG * zy;
    float zz = xlz + xrz + er.z; zz = zz > 0.f ? zz : NEG * zz;
    float zw = xlw + xrw + er.w; zw = zw > 0.f ? zw : NEG * zw;
    float p = zx * at.x + zy * at.y + zz * at.z + zw * at.w;
    p += __shfl_xor(p, 1, 64);
    p += __shfl_xor(p, 2, 64);
    p += __shfl_xor(p, 4, 64);
    p += __shfl_xor(p, 8, 64);
    p += __shfl_xor(p, 16, 64);
    float mnew = fmaxf(m, p);
    float corr = __expf(m - mnew);
    float wgt = __expf(p - mnew);
    denom = denom * corr + wgt;
    acc.x = acc.x * corr + wgt * xlx;
    acc.y = acc.y * corr + wgt * xly;
    acc.z = acc.z * corr + wgt * xlz;
    acc.w = acc.w * corr + wgt * xlw;
    m = mnew;
  }
  float inv = 1.f / (denom + 1e-16f);
  acc.x *= inv; acc.y *= inv; acc.z *= inv; acc.w *= inv;
  float ox = acc.x + __shfl_xor(acc.x, 32, 64);
  float oy = acc.y + __shfl_xor(acc.y, 32, 64);
  float oz = acc.z + __shfl_xor(acc.z, 32, 64);
  float ow = acc.w + __shfl_xor(acc.w, 32, 64);
  if (lane < 32) {
    float4 b4 = *(const float4*)(bias + d);
    *(float4*)(out + (size_t)t * D + d) =
        make_float4(ox * 0.5f + b4.x, oy * 0.5f + b4.y, oz * 0.5f + b4.z, ow * 0.5f + b4.w);
  }
}

extern "C" void kernel_launch(void* const* d_in, const int* in_sizes, int n_in,
                              void* d_out, int out_size, void* d_ws, size_t ws_size,
                              hipStream_t stream) {
  const float* queries = (const float*)d_in[0];
  const float* entities = (const float*)d_in[1];
  const int* edge_index = (const int*)d_in[2];
  const float* relations = (const float*)d_in[3];
  const int* relation_index = (const int*)d_in[4];
  const int* batch = (const int*)d_in[5];
  const float* W_l = (const float*)d_in[6];
  const float* b_l = (const float*)d_in[7];
  const float* W_r = (const float*)d_in[8];
  const float* b_r = (const float*)d_in[9];
  const float* W_ea = (const float*)d_in[10];
  const float* att = (const float*)d_in[11];
  const float* bias = (const float*)d_in[12];
  const float* W_le = (const float*)d_in[13];
  const float* b_le = (const float*)d_in[14];

  float* out_node = (float*)d_out;
  float* out_edge = out_node + (size_t)N_ENT * D;

  char* base = (char*)d_ws;
  size_t off = 0;
  auto take = [&](size_t nbytes) -> void* {
    void* p = base + off;
    off += (nbytes + 255) & ~(size_t)255;
    return p;
  };
  unsigned short* x_l = (unsigned short*)take((size_t)NTOT * HD * sizeof(unsigned short)); // 51.2 MB
  unsigned short* x_r = (unsigned short*)take((size_t)NTOT * HD * sizeof(unsigned short)); // 51.2 MB
  float* e_rel = (float*)take((size_t)(RCOUNT + 1) * HD * sizeof(float));                  // 513 KB
  int* counts = (int*)take((size_t)N_ENT * sizeof(int));
  int* offsets = (int*)take((size_t)(N_ENT + 1) * sizeof(int));
  int* cursor = (int*)take((size_t)N_ENT * sizeof(int));
  int* bsum = (int*)take(512 * sizeof(int));
  int* bpre = (int*)take(512 * sizeof(int));
  unsigned int* sorted = (unsigned int*)take((size_t)ETOT * sizeof(unsigned int));         // 2 MB

  k_rel<<<dim3(RCOUNT + 1), dim3(256), 0, stream>>>(relations, W_ea, W_le, b_le, e_rel, out_edge);
  k_gemm_mfma<<<dim3((NTOT + 127) / 128, 4), dim3(256), 0, stream>>>(entities, queries, W_l, b_l, W_r, b_r, x_l, x_r);
  k_zero<<<dim3((N_ENT + 255) / 256), dim3(256), 0, stream>>>(counts);
  k_hist<<<dim3((ETOT + 255) / 256), dim3(256), 0, stream>>>(edge_index, counts);
  k_scan1<<<dim3(SCAN_NB), dim3(256), 0, stream>>>(counts, bsum);
  k_scan2<<<dim3(1), dim3(512), 0, stream>>>(bsum, bpre);
  k_scan3<<<dim3(SCAN_NB), dim3(256), 0, stream>>>(counts, bpre, offsets, cursor);
  k_scatter<<<dim3((ETOT + 255) / 256), dim3(256), 0, stream>>>(edge_index, relation_index, batch, cursor, sorted);
  k_edge<<<dim3(N_ENT / 4), dim3(256), 0, stream>>>(x_l, x_r, e_rel, offsets, sorted, att, bias, out_node);
}

// Round 3
// 334.411 us; speedup vs baseline: 1.5631x; 1.1849x over previous
//
#include <hip/hip_runtime.h>
#include <math.h>

#define D 128
#define HD 256
#define N_ENT 100000
#define NBATCH 64
#define NTOT (N_ENT + NBATCH)   // 100064
#define RCOUNT 500
#define E_BASE 400000
#define ETOT (E_BASE + N_ENT)   // 500000
#define NEG 0.2f
#define SCAN_NB 391             // ceil(100000/256)

typedef __attribute__((ext_vector_type(8))) short bf16x8;
typedef __attribute__((ext_vector_type(8))) unsigned short u16x8;
typedef __attribute__((ext_vector_type(4))) float f32x4;

static __device__ __forceinline__ unsigned short f2bf(float f) {
  unsigned u = __builtin_bit_cast(unsigned, f);
  u += 0x7fffu + ((u >> 16) & 1u);   // RNE
  return (unsigned short)(u >> 16);
}
static __device__ __forceinline__ float bf2f(unsigned short h) {
  return __builtin_bit_cast(float, (unsigned)h << 16);
}

// ---------------- W cast: Wbf[512][128] = [W_l; W_r] in bf16 ----------------
__global__ __launch_bounds__(256) void k_wcast(
    const float* __restrict__ W_l, const float* __restrict__ W_r,
    unsigned short* __restrict__ Wbf) {
  int idx = blockIdx.x * 256 + threadIdx.x;   // 16384 threads, 4 elems each
  int e4 = idx * 4;
  int v = e4 >> 7;          // virtual row 0..511
  int k = e4 & 127;
  const float* src = (v < HD) ? (W_l + (size_t)v * D + k) : (W_r + (size_t)(v - HD) * D + k);
  float4 a = *(const float4*)src;
  *(ushort4*)(Wbf + (size_t)v * D + k) = make_ushort4(f2bf(a.x), f2bf(a.y), f2bf(a.z), f2bf(a.w));
}

// ---------------- e_rel (501x256, bf16) + out_edge (500x128, fp32) ----------------
__global__ __launch_bounds__(256) void k_rel(
    const float* __restrict__ relations, const float* __restrict__ W_ea,
    const float* __restrict__ W_le, const float* __restrict__ b_le,
    unsigned short* __restrict__ e_rel, float* __restrict__ out_edge) {
  __shared__ float relu_p[HD];
  int r = blockIdx.x;
  int j = threadIdx.x;
  const float* w = W_ea + (size_t)j * D;
  float acc = 0.f;
  if (r < RCOUNT) {
    const float* rel = relations + (size_t)r * D;
    for (int k = 0; k < D; k += 4) {
      float4 a = *(const float4*)(rel + k);
      float4 b = *(const float4*)(w + k);
      acc += a.x * b.x + a.y * b.y + a.z * b.z + a.w * b.w;
    }
  } else {  // all-ones rel_feat row -> row sums of W_ea
    for (int k = 0; k < D; k += 4) {
      float4 b = *(const float4*)(w + k);
      acc += b.x + b.y + b.z + b.w;
    }
  }
  e_rel[(size_t)r * HD + j] = f2bf(acc);
  if (r < RCOUNT) {
    relu_p[j] = acc > 0.f ? acc : 0.f;
    __syncthreads();
    if (j < D) {
      const float* wl = W_le + (size_t)j * HD;
      float o = b_le[j];
      for (int k = 0; k < HD; k += 4) {
        float4 p4 = *(const float4*)(relu_p + k);
        float4 w4 = *(const float4*)(wl + k);
        o += p4.x * w4.x + p4.y * w4.y + p4.z * w4.z + p4.w * w4.w;
      }
      out_edge[(size_t)r * D + j] = o;
    }
  }
}

// ---------------- MFMA GEMM: 64-row x 256-col blocks, B direct from cache ----------------
#define LDA 136  // LDS row stride in ushort (272 B: 16B-aligned, bank-shift 4/row)

__global__ __launch_bounds__(256) void k_gemm_mfma(
    const float* __restrict__ entities, const float* __restrict__ queries,
    const unsigned short* __restrict__ Wbf,
    const float* __restrict__ b_l, const float* __restrict__ b_r,
    unsigned short* __restrict__ x_l, unsigned short* __restrict__ x_r) {
  __shared__ unsigned short As[64 * LDA];
  __shared__ unsigned short Cs[64 * LDA];
  int rb = blockIdx.x;          // 64-row tile
  int gy = blockIdx.y;          // 0 -> x_l, 1 -> x_r
  int tid = threadIdx.x;

  // ---- stage A (fp32 -> bf16) ----
  {
    int rr = tid >> 2;                 // 0..63
    int part = (tid & 3) * 32;
    int row = rb * 64 + rr;
    const float* sp;
    if (row < N_ENT) sp = entities + (size_t)row * D;
    else if (row < NTOT) sp = queries + (size_t)(row - N_ENT) * D;
    else sp = entities;  // dummy; stores guarded
#pragma unroll
    for (int k = 0; k < 32; k += 8) {
      float4 a0 = *(const float4*)(sp + part + k);
      float4 a1 = *(const float4*)(sp + part + k + 4);
      u16x8 p;
      p[0] = f2bf(a0.x); p[1] = f2bf(a0.y); p[2] = f2bf(a0.z); p[3] = f2bf(a0.w);
      p[4] = f2bf(a1.x); p[5] = f2bf(a1.y); p[6] = f2bf(a1.z); p[7] = f2bf(a1.w);
      *(u16x8*)(&As[rr * LDA + part + k]) = p;
    }
  }
  __syncthreads();

  int w = tid >> 6, lane = tid & 63;
  int wr = w >> 1, wc = w & 1;          // 2x2 wave grid; wave tile 32x64 per chunk
  int m = lane & 15, q8 = (lane >> 4) * 8;
  const float* bv = gy ? b_r : b_l;
  unsigned short* xdst = gy ? x_r : x_l;

  for (int cc = 0; cc < 2; cc++) {
    f32x4 acc[2][4];
#pragma unroll
    for (int i = 0; i < 2; i++)
#pragma unroll
      for (int j = 0; j < 4; j++) acc[i][j] = (f32x4){0.f, 0.f, 0.f, 0.f};

    const unsigned short* wbase = Wbf + (size_t)(gy * 256 + cc * 128 + wc * 64 + m) * D;
#pragma unroll
    for (int ks = 0; ks < 128; ks += 32) {
      bf16x8 af[2], bfr[4];
#pragma unroll
      for (int i = 0; i < 2; i++)
        af[i] = *(const bf16x8*)(&As[(wr * 32 + i * 16 + m) * LDA + ks + q8]);
#pragma unroll
      for (int j = 0; j < 4; j++)
        bfr[j] = *(const bf16x8*)(wbase + (size_t)j * 16 * D + ks + q8);
#pragma unroll
      for (int i = 0; i < 2; i++)
#pragma unroll
        for (int j = 0; j < 4; j++)
          acc[i][j] = __builtin_amdgcn_mfma_f32_16x16x32_bf16(af[i], bfr[j], acc[i][j], 0, 0, 0);
    }

    __syncthreads();  // prior chunk's store-phase LDS reads complete
    // write acc -> Cs (row-major, +bias, bf16). C layout: col=lane&15, row=(lane>>4)*4+reg
#pragma unroll
    for (int j = 0; j < 4; j++) {
      int col = wc * 64 + j * 16 + m;
      float bb = bv[cc * 128 + col];
#pragma unroll
      for (int i = 0; i < 2; i++) {
        int row0 = wr * 32 + i * 16 + (lane >> 4) * 4;
#pragma unroll
        for (int r = 0; r < 4; r++)
          Cs[(row0 + r) * LDA + col] = f2bf(acc[i][j][r] + bb);
      }
    }
    __syncthreads();
    // coalesced global store: 64 rows x 128 cols bf16, 16B per thread-iter
#pragma unroll
    for (int it = 0; it < 4; it++) {
      int g = it * 256 + tid;
      int row = g >> 4, c8 = (g & 15) * 8;
      int grow = rb * 64 + row;
      if (grow < NTOT) {
        u16x8 v = *(const u16x8*)(&Cs[row * LDA + c8]);
        *(u16x8*)(xdst + (size_t)grow * HD + cc * 128 + c8) = v;
      }
    }
  }
}

// ---------------- counting sort of edges by target ----------------
__global__ void k_zero(int* __restrict__ counts) {
  int i = blockIdx.x * 256 + threadIdx.x;
  if (i < N_ENT) counts[i] = 0;
}

__global__ void k_hist(const int* __restrict__ edge_index, int* __restrict__ counts) {
  int e = blockIdx.x * 256 + threadIdx.x;
  if (e >= ETOT) return;
  int t = (e < E_BASE) ? edge_index[E_BASE + e] : (e - E_BASE);
  atomicAdd(counts + t, 1);
}

__global__ void k_scan1(const int* __restrict__ counts, int* __restrict__ bsum) {
  __shared__ int sdata[256];
  int i = blockIdx.x * 256 + threadIdx.x;
  sdata[threadIdx.x] = (i < N_ENT) ? counts[i] : 0;
  __syncthreads();
  for (int off = 128; off > 0; off >>= 1) {
    if (threadIdx.x < off) sdata[threadIdx.x] += sdata[threadIdx.x + off];
    __syncthreads();
  }
  if (threadIdx.x == 0) bsum[blockIdx.x] = sdata[0];
}

__global__ void k_scan2(const int* __restrict__ bsum, int* __restrict__ bpre) {
  __shared__ int s[512];
  int tid = threadIdx.x;
  s[tid] = (tid < SCAN_NB) ? bsum[tid] : 0;
  __syncthreads();
  for (int off = 1; off < 512; off <<= 1) {
    int y = (tid >= off) ? s[tid - off] : 0;
    __syncthreads();
    s[tid] += y;
    __syncthreads();
  }
  bpre[tid] = (tid == 0) ? 0 : s[tid - 1];
}

__global__ void k_scan3(const int* __restrict__ counts, const int* __restrict__ bpre,
                        int* __restrict__ offsets, int* __restrict__ cursor) {
  __shared__ int s[256];
  int tid = threadIdx.x;
  int i = blockIdx.x * 256 + tid;
  int v = (i < N_ENT) ? counts[i] : 0;
  s[tid] = v;
  __syncthreads();
  for (int off = 1; off < 256; off <<= 1) {
    int y = (tid >= off) ? s[tid - off] : 0;
    __syncthreads();
    s[tid] += y;
    __syncthreads();
  }
  int excl = bpre[blockIdx.x] + s[tid] - v;
  if (i <= N_ENT) offsets[i] = excl;   // i==N_ENT -> total == ETOT
  if (i < N_ENT) cursor[i] = excl;
}

__global__ void k_scatter(const int* __restrict__ edge_index, const int* __restrict__ relation_index,
                          const int* __restrict__ batch, int* __restrict__ cursor,
                          unsigned int* __restrict__ sorted) {
  int e = blockIdx.x * 256 + threadIdx.x;
  if (e >= ETOT) return;
  int s, t, r;
  if (e < E_BASE) {
    s = edge_index[e];
    t = edge_index[E_BASE + e];
    r = relation_index[e];
  } else {
    int i = e - E_BASE;
    s = N_ENT + batch[i];
    t = i;
    r = RCOUNT;
  }
  int pos = atomicAdd(cursor + t, 1);
  sorted[pos] = (unsigned)s | ((unsigned)r << 17);  // s<2^17, r<2^9
}

// ---------------- per-target aggregate; NO online max (|p|<~12, exp cannot overflow) ----------------
__global__ __launch_bounds__(256) void k_edge(
    const unsigned short* __restrict__ x_l, const unsigned short* __restrict__ x_r,
    const unsigned short* __restrict__ e_rel, const int* __restrict__ offsets,
    const unsigned int* __restrict__ sorted, const float* __restrict__ att,
    const float* __restrict__ bias, float* __restrict__ out) {
  int wv = threadIdx.x >> 6;
  int lane = threadIdx.x & 63;
  int t = blockIdx.x * 4 + wv;  // grid is exactly N_ENT/4
  int elem = lane * 4;
  int d = elem & (D - 1);
  ushort4 xr4 = *(const ushort4*)(x_r + (size_t)t * HD + elem);
  float xrx = bf2f(xr4.x), xry = bf2f(xr4.y), xrz = bf2f(xr4.z), xrw = bf2f(xr4.w);
  float4 at = *(const float4*)(att + elem);
  int e0 = offsets[t], e1 = offsets[t + 1];
  float denom = 0.f;
  float4 acc = make_float4(0.f, 0.f, 0.f, 0.f);
  for (int e = e0; e < e1; e++) {
    unsigned sr = sorted[e];
    int s = sr & 0x1FFFF;
    int r = sr >> 17;
    ushort4 xl4 = *(const ushort4*)(x_l + (size_t)s * HD + elem);
    ushort4 er4 = *(const ushort4*)(e_rel + (size_t)r * HD + elem);
    float xlx = bf2f(xl4.x), xly = bf2f(xl4.y), xlz = bf2f(xl4.z), xlw = bf2f(xl4.w);
    float zx = xlx + xrx + bf2f(er4.x); zx = zx > 0.f ? zx : NEG * zx;
    float zy = xly + xry + bf2f(er4.y); zy = zy > 0.f ? zy : NEG * zy;
    float zz = xlz + xrz + bf2f(er4.z); zz = zz > 0.f ? zz : NEG * zz;
    float zw = xlw + xrw + bf2f(er4.w); zw = zw > 0.f ? zw : NEG * zw;
    float p = zx * at.x + zy * at.y + zz * at.z + zw * at.w;
    p += __shfl_xor(p, 1, 64);
    p += __shfl_xor(p, 2, 64);
    p += __shfl_xor(p, 4, 64);
    p += __shfl_xor(p, 8, 64);
    p += __shfl_xor(p, 16, 64);
    float wgt = __expf(p);
    denom += wgt;
    acc.x += wgt * xlx;
    acc.y += wgt * xly;
    acc.z += wgt * xlz;
    acc.w += wgt * xlw;
  }
  float inv = 1.f / (denom + 1e-16f);
  acc.x *= inv; acc.y *= inv; acc.z *= inv; acc.w *= inv;
  float ox = acc.x + __shfl_xor(acc.x, 32, 64);
  float oy = acc.y + __shfl_xor(acc.y, 32, 64);
  float oz = acc.z + __shfl_xor(acc.z, 32, 64);
  float ow = acc.w + __shfl_xor(acc.w, 32, 64);
  if (lane < 32) {
    float4 b4 = *(const float4*)(bias + d);
    *(float4*)(out + (size_t)t * D + d) =
        make_float4(ox * 0.5f + b4.x, oy * 0.5f + b4.y, oz * 0.5f + b4.z, ow * 0.5f + b4.w);
  }
}

extern "C" void kernel_launch(void* const* d_in, const int* in_sizes, int n_in,
                              void* d_out, int out_size, void* d_ws, size_t ws_size,
                              hipStream_t stream) {
  const float* queries = (const float*)d_in[0];
  const float* entities = (const float*)d_in[1];
  const int* edge_index = (const int*)d_in[2];
  const float* relations = (const float*)d_in[3];
  const int* relation_index = (const int*)d_in[4];
  const int* batch = (const int*)d_in[5];
  const float* W_l = (const float*)d_in[6];
  const float* b_l = (const float*)d_in[7];
  const float* W_r = (const float*)d_in[8];
  const float* b_r = (const float*)d_in[9];
  const float* W_ea = (const float*)d_in[10];
  const float* att = (const float*)d_in[11];
  const float* bias = (const float*)d_in[12];
  const float* W_le = (const float*)d_in[13];
  const float* b_le = (const float*)d_in[14];

  float* out_node = (float*)d_out;
  float* out_edge = out_node + (size_t)N_ENT * D;

  char* base = (char*)d_ws;
  size_t off = 0;
  auto take = [&](size_t nbytes) -> void* {
    void* p = base + off;
    off += (nbytes + 255) & ~(size_t)255;
    return p;
  };
  unsigned short* x_l = (unsigned short*)take((size_t)NTOT * HD * sizeof(unsigned short)); // 51.2 MB
  unsigned short* x_r = (unsigned short*)take((size_t)NTOT * HD * sizeof(unsigned short)); // 51.2 MB
  unsigned short* e_rel = (unsigned short*)take((size_t)(RCOUNT + 1) * HD * sizeof(unsigned short));
  unsigned short* Wbf = (unsigned short*)take((size_t)512 * D * sizeof(unsigned short));   // 128 KB
  int* counts = (int*)take((size_t)N_ENT * sizeof(int));
  int* offsets = (int*)take((size_t)(N_ENT + 1) * sizeof(int));
  int* cursor = (int*)take((size_t)N_ENT * sizeof(int));
  int* bsum = (int*)take(512 * sizeof(int));
  int* bpre = (int*)take(512 * sizeof(int));
  unsigned int* sorted = (unsigned int*)take((size_t)ETOT * sizeof(unsigned int));         // 2 MB

  k_wcast<<<dim3(64), dim3(256), 0, stream>>>(W_l, W_r, Wbf);
  k_rel<<<dim3(RCOUNT + 1), dim3(256), 0, stream>>>(relations, W_ea, W_le, b_le, e_rel, out_edge);
  k_gemm_mfma<<<dim3((NTOT + 63) / 64, 2), dim3(256), 0, stream>>>(entities, queries, Wbf, b_l, b_r, x_l, x_r);
  k_zero<<<dim3((N_ENT + 255) / 256), dim3(256), 0, stream>>>(counts);
  k_hist<<<dim3((ETOT + 255) / 256), dim3(256), 0, stream>>>(edge_index, counts);
  k_scan1<<<dim3(SCAN_NB), dim3(256), 0, stream>>>(counts, bsum);
  k_scan2<<<dim3(1), dim3(512), 0, stream>>>(bsum, bpre);
  k_scan3<<<dim3(SCAN_NB), dim3(256), 0, stream>>>(counts, bpre, offsets, cursor);
  k_scatter<<<dim3((ETOT + 255) / 256), dim3(256), 0, stream>>>(edge_index, relation_index, batch, cursor, sorted);
  k_edge<<<dim3(N_ENT / 4), dim3(256), 0, stream>>>(x_l, x_r, e_rel, offsets, sorted, att, bias, out_node);
}

// Round 4
// 319.171 us; speedup vs baseline: 1.6377x; 1.0478x over previous
//
#include <hip/hip_runtime.h>
#include <math.h>

#define D 128
#define HD 256
#define N_ENT 100000
#define NBATCH 64
#define NTOT (N_ENT + NBATCH)   // 100064
#define RCOUNT 500
#define E_BASE 400000
#define ETOT (E_BASE + N_ENT)   // 500000
#define NEG 0.2f
#define SCAN_NB 391             // ceil(100000/256)

typedef __attribute__((ext_vector_type(8))) short bf16x8;
typedef __attribute__((ext_vector_type(8))) unsigned short u16x8;
typedef __attribute__((ext_vector_type(4))) float f32x4;

static __device__ __forceinline__ unsigned short f2bf(float f) {
  unsigned u = __builtin_bit_cast(unsigned, f);
  u += 0x7fffu + ((u >> 16) & 1u);   // RNE
  return (unsigned short)(u >> 16);
}
static __device__ __forceinline__ float bf2f(unsigned short h) {
  return __builtin_bit_cast(float, (unsigned)h << 16);
}

// ---------------- W cast: Wbf[512][128] = [W_l; W_r] in bf16 ----------------
__global__ __launch_bounds__(256) void k_wcast(
    const float* __restrict__ W_l, const float* __restrict__ W_r,
    unsigned short* __restrict__ Wbf) {
  int idx = blockIdx.x * 256 + threadIdx.x;   // 16384 threads, 4 elems each
  int e4 = idx * 4;
  int v = e4 >> 7;          // virtual row 0..511
  int k = e4 & 127;
  const float* src = (v < HD) ? (W_l + (size_t)v * D + k) : (W_r + (size_t)(v - HD) * D + k);
  float4 a = *(const float4*)src;
  *(ushort4*)(Wbf + (size_t)v * D + k) = make_ushort4(f2bf(a.x), f2bf(a.y), f2bf(a.z), f2bf(a.w));
}

// ---------------- e_rel (501x256, bf16) + out_edge (500x128, fp32) ----------------
__global__ __launch_bounds__(256) void k_rel(
    const float* __restrict__ relations, const float* __restrict__ W_ea,
    const float* __restrict__ W_le, const float* __restrict__ b_le,
    unsigned short* __restrict__ e_rel, float* __restrict__ out_edge) {
  __shared__ float relu_p[HD];
  int r = blockIdx.x;
  int j = threadIdx.x;
  const float* w = W_ea + (size_t)j * D;
  float acc = 0.f;
  if (r < RCOUNT) {
    const float* rel = relations + (size_t)r * D;
    for (int k = 0; k < D; k += 4) {
      float4 a = *(const float4*)(rel + k);
      float4 b = *(const float4*)(w + k);
      acc += a.x * b.x + a.y * b.y + a.z * b.z + a.w * b.w;
    }
  } else {  // all-ones rel_feat row -> row sums of W_ea
    for (int k = 0; k < D; k += 4) {
      float4 b = *(const float4*)(w + k);
      acc += b.x + b.y + b.z + b.w;
    }
  }
  e_rel[(size_t)r * HD + j] = f2bf(acc);
  if (r < RCOUNT) {
    relu_p[j] = acc > 0.f ? acc : 0.f;
    __syncthreads();
    if (j < D) {
      const float* wl = W_le + (size_t)j * HD;
      float o = b_le[j];
      for (int k = 0; k < HD; k += 4) {
        float4 p4 = *(const float4*)(relu_p + k);
        float4 w4 = *(const float4*)(wl + k);
        o += p4.x * w4.x + p4.y * w4.y + p4.z * w4.z + p4.w * w4.w;
      }
      out_edge[(size_t)r * D + j] = o;
    }
  }
}

// ---------------- MFMA GEMM: 64-row block, A staged ONCE, all 512 virtual cols ----------------
#define LDA 136  // LDS row stride in ushort (272 B: 16B-aligned, bank-shift 4/row)

__global__ __launch_bounds__(256) void k_gemm_mfma(
    const float* __restrict__ entities, const float* __restrict__ queries,
    const unsigned short* __restrict__ Wbf,
    const float* __restrict__ b_l, const float* __restrict__ b_r,
    unsigned short* __restrict__ x_l, unsigned short* __restrict__ x_r) {
  __shared__ unsigned short As[64 * LDA];
  __shared__ unsigned short Cs[64 * LDA];
  int rb = blockIdx.x;          // 64-row tile
  int tid = threadIdx.x;

  // ---- stage A (fp32 -> bf16), once ----
  {
    int rr = tid >> 2;                 // 0..63
    int part = (tid & 3) * 32;
    int row = rb * 64 + rr;
    const float* sp;
    if (row < N_ENT) sp = entities + (size_t)row * D;
    else if (row < NTOT) sp = queries + (size_t)(row - N_ENT) * D;
    else sp = entities;  // dummy; stores guarded
#pragma unroll
    for (int k = 0; k < 32; k += 8) {
      float4 a0 = *(const float4*)(sp + part + k);
      float4 a1 = *(const float4*)(sp + part + k + 4);
      u16x8 p;
      p[0] = f2bf(a0.x); p[1] = f2bf(a0.y); p[2] = f2bf(a0.z); p[3] = f2bf(a0.w);
      p[4] = f2bf(a1.x); p[5] = f2bf(a1.y); p[6] = f2bf(a1.z); p[7] = f2bf(a1.w);
      *(u16x8*)(&As[rr * LDA + part + k]) = p;
    }
  }
  __syncthreads();

  int w = tid >> 6, lane = tid & 63;
  int wr = w >> 1, wc = w & 1;          // 2x2 wave grid per 128-col chunk
  int m = lane & 15, q8 = (lane >> 4) * 8;

  for (int ccv = 0; ccv < 4; ccv++) {   // virtual col chunks of 128 (0,1->x_l; 2,3->x_r)
    bool isL = ccv < 2;
    const float* bv = isL ? b_l : b_r;
    unsigned short* xdst = isL ? x_l : x_r;
    int cbase = (ccv & 1) * 128;

    f32x4 acc[2][4];
#pragma unroll
    for (int i = 0; i < 2; i++)
#pragma unroll
      for (int j = 0; j < 4; j++) acc[i][j] = (f32x4){0.f, 0.f, 0.f, 0.f};

    const unsigned short* wbase = Wbf + (size_t)(ccv * 128 + wc * 64 + m) * D;
#pragma unroll
    for (int ks = 0; ks < 128; ks += 32) {
      bf16x8 af[2], bfr[4];
#pragma unroll
      for (int i = 0; i < 2; i++)
        af[i] = *(const bf16x8*)(&As[(wr * 32 + i * 16 + m) * LDA + ks + q8]);
#pragma unroll
      for (int j = 0; j < 4; j++)
        bfr[j] = *(const bf16x8*)(wbase + (size_t)j * 16 * D + ks + q8);
#pragma unroll
      for (int i = 0; i < 2; i++)
#pragma unroll
        for (int j = 0; j < 4; j++)
          acc[i][j] = __builtin_amdgcn_mfma_f32_16x16x32_bf16(af[i], bfr[j], acc[i][j], 0, 0, 0);
    }

    __syncthreads();  // prior chunk's store-phase Cs reads complete
    // acc -> Cs (row-major, +bias, bf16). C layout: col=lane&15, row=(lane>>4)*4+reg
#pragma unroll
    for (int j = 0; j < 4; j++) {
      int col = wc * 64 + j * 16 + m;
      float bb = bv[cbase + col];
#pragma unroll
      for (int i = 0; i < 2; i++) {
        int row0 = wr * 32 + i * 16 + (lane >> 4) * 4;
#pragma unroll
        for (int r = 0; r < 4; r++)
          Cs[(row0 + r) * LDA + col] = f2bf(acc[i][j][r] + bb);
      }
    }
    __syncthreads();
    // coalesced global store: 64 rows x 128 cols bf16, 16B/thread-iter
#pragma unroll
    for (int it = 0; it < 4; it++) {
      int g = it * 256 + tid;
      int row = g >> 4, c8 = (g & 15) * 8;
      int grow = rb * 64 + row;
      if (grow < NTOT) {
        u16x8 v = *(const u16x8*)(&Cs[row * LDA + c8]);
        *(u16x8*)(xdst + (size_t)grow * HD + cbase + c8) = v;
      }
    }
  }
}

// ---------------- counting sort of edges by target ----------------
__global__ void k_zero(int* __restrict__ counts) {
  int i = blockIdx.x * 256 + threadIdx.x;
  if (i < N_ENT) counts[i] = 0;
}

__global__ void k_hist(const int* __restrict__ edge_index, int* __restrict__ counts) {
  int e = blockIdx.x * 256 + threadIdx.x;
  if (e >= ETOT) return;
  int t = (e < E_BASE) ? edge_index[E_BASE + e] : (e - E_BASE);
  atomicAdd(counts + t, 1);
}

__global__ void k_scan1(const int* __restrict__ counts, int* __restrict__ bsum) {
  __shared__ int sdata[256];
  int i = blockIdx.x * 256 + threadIdx.x;
  sdata[threadIdx.x] = (i < N_ENT) ? counts[i] : 0;
  __syncthreads();
  for (int off = 128; off > 0; off >>= 1) {
    if (threadIdx.x < off) sdata[threadIdx.x] += sdata[threadIdx.x + off];
    __syncthreads();
  }
  if (threadIdx.x == 0) bsum[blockIdx.x] = sdata[0];
}

__global__ void k_scan2(const int* __restrict__ bsum, int* __restrict__ bpre) {
  __shared__ int s[512];
  int tid = threadIdx.x;
  s[tid] = (tid < SCAN_NB) ? bsum[tid] : 0;
  __syncthreads();
  for (int off = 1; off < 512; off <<= 1) {
    int y = (tid >= off) ? s[tid - off] : 0;
    __syncthreads();
    s[tid] += y;
    __syncthreads();
  }
  bpre[tid] = (tid == 0) ? 0 : s[tid - 1];
}

__global__ void k_scan3(const int* __restrict__ counts, const int* __restrict__ bpre,
                        int* __restrict__ offsets, int* __restrict__ cursor) {
  __shared__ int s[256];
  int tid = threadIdx.x;
  int i = blockIdx.x * 256 + tid;
  int v = (i < N_ENT) ? counts[i] : 0;
  s[tid] = v;
  __syncthreads();
  for (int off = 1; off < 256; off <<= 1) {
    int y = (tid >= off) ? s[tid - off] : 0;
    __syncthreads();
    s[tid] += y;
    __syncthreads();
  }
  int excl = bpre[blockIdx.x] + s[tid] - v;
  if (i <= N_ENT) offsets[i] = excl;   // i==N_ENT -> total == ETOT
  if (i < N_ENT) cursor[i] = excl;
}

__global__ void k_scatter(const int* __restrict__ edge_index, const int* __restrict__ relation_index,
                          const int* __restrict__ batch, int* __restrict__ cursor,
                          unsigned int* __restrict__ sorted) {
  int e = blockIdx.x * 256 + threadIdx.x;
  if (e >= ETOT) return;
  int s, t, r;
  if (e < E_BASE) {
    s = edge_index[e];
    t = edge_index[E_BASE + e];
    r = relation_index[e];
  } else {
    int i = e - E_BASE;
    s = N_ENT + batch[i];
    t = i;
    r = RCOUNT;
  }
  int pos = atomicAdd(cursor + t, 1);
  sorted[pos] = (unsigned)s | ((unsigned)r << 17);  // s<2^17, r<2^9
}

// ---------------- per-target aggregate: 2 edges/iter, 8 elems/lane ----------------
// lanes 0-31: edge e; lanes 32-63: edge e+1. Within 32: lanes 0-15 head0, 16-31 head1.
__global__ __launch_bounds__(256) void k_edge(
    const unsigned short* __restrict__ x_l, const unsigned short* __restrict__ x_r,
    const unsigned short* __restrict__ e_rel, const int* __restrict__ offsets,
    const unsigned int* __restrict__ sorted, const float* __restrict__ att,
    const float* __restrict__ bias, float* __restrict__ out) {
  int wv = threadIdx.x >> 6;
  int lane = threadIdx.x & 63;
  int t = blockIdx.x * 4 + wv;  // grid is exactly N_ENT/4
  int half = lane >> 5;         // which edge of the pair
  int sl = lane & 31;
  int elem = sl * 8;            // elems 8sl..8sl+7; head = sl>>4
  u16x8 xr8 = *(const u16x8*)(x_r + (size_t)t * HD + elem);
  float xr[8], at[8];
#pragma unroll
  for (int i = 0; i < 8; i++) xr[i] = bf2f(xr8[i]);
  float4 at0 = *(const float4*)(att + elem);
  float4 at1 = *(const float4*)(att + elem + 4);
  at[0] = at0.x; at[1] = at0.y; at[2] = at0.z; at[3] = at0.w;
  at[4] = at1.x; at[5] = at1.y; at[6] = at1.z; at[7] = at1.w;
  int e0 = offsets[t], e1 = offsets[t + 1];
  float denom = 0.f;
  float acc[8];
#pragma unroll
  for (int i = 0; i < 8; i++) acc[i] = 0.f;

  for (int e = e0; e < e1; e += 2) {
    int ee = e + half;
    bool valid = ee < e1;
    if (!valid) ee = e;
    unsigned sr = sorted[ee];
    int s = sr & 0x1FFFF;
    int r = sr >> 17;
    u16x8 xl8 = *(const u16x8*)(x_l + (size_t)s * HD + elem);
    u16x8 er8 = *(const u16x8*)(e_rel + (size_t)r * HD + elem);
    float xl[8];
    float p = 0.f;
#pragma unroll
    for (int i = 0; i < 8; i++) {
      xl[i] = bf2f(xl8[i]);
      float z = xl[i] + xr[i] + bf2f(er8[i]);
      z = z > 0.f ? z : NEG * z;
      p += z * at[i];
    }
    // reduce over the 16-lane head group
    p += __shfl_xor(p, 1, 64);
    p += __shfl_xor(p, 2, 64);
    p += __shfl_xor(p, 4, 64);
    p += __shfl_xor(p, 8, 64);
    float wgt = valid ? __expf(p) : 0.f;
    denom += wgt;
#pragma unroll
    for (int i = 0; i < 8; i++) acc[i] += wgt * xl[i];
  }
  // combine the two edge-halves (same target, same head layout)
  denom += __shfl_xor(denom, 32, 64);
#pragma unroll
  for (int i = 0; i < 8; i++) acc[i] += __shfl_xor(acc[i], 32, 64);
  // normalize per head (denom is head-specific per 16-lane group)
  float inv = 1.f / (denom + 1e-16f);
  float o[8];
#pragma unroll
  for (int i = 0; i < 8; i++) o[i] = acc[i] * inv;
  // combine heads: lane sl (head0, d=8sl..) with lane sl^16 (head1, same d)
#pragma unroll
  for (int i = 0; i < 8; i++) o[i] += __shfl_xor(o[i], 16, 64);
  if (lane < 16) {
    int d = sl * 8;
    float4 b0 = *(const float4*)(bias + d);
    float4 b1 = *(const float4*)(bias + d + 4);
    *(float4*)(out + (size_t)t * D + d) =
        make_float4(o[0] * 0.5f + b0.x, o[1] * 0.5f + b0.y, o[2] * 0.5f + b0.z, o[3] * 0.5f + b0.w);
    *(float4*)(out + (size_t)t * D + d + 4) =
        make_float4(o[4] * 0.5f + b1.x, o[5] * 0.5f + b1.y, o[6] * 0.5f + b1.z, o[7] * 0.5f + b1.w);
  }
}

extern "C" void kernel_launch(void* const* d_in, const int* in_sizes, int n_in,
                              void* d_out, int out_size, void* d_ws, size_t ws_size,
                              hipStream_t stream) {
  const float* queries = (const float*)d_in[0];
  const float* entities = (const float*)d_in[1];
  const int* edge_index = (const int*)d_in[2];
  const float* relations = (const float*)d_in[3];
  const int* relation_index = (const int*)d_in[4];
  const int* batch = (const int*)d_in[5];
  const float* W_l = (const float*)d_in[6];
  const float* b_l = (const float*)d_in[7];
  const float* W_r = (const float*)d_in[8];
  const float* b_r = (const float*)d_in[9];
  const float* W_ea = (const float*)d_in[10];
  const float* att = (const float*)d_in[11];
  const float* bias = (const float*)d_in[12];
  const float* W_le = (const float*)d_in[13];
  const float* b_le = (const float*)d_in[14];

  float* out_node = (float*)d_out;
  float* out_edge = out_node + (size_t)N_ENT * D;

  char* base = (char*)d_ws;
  size_t off = 0;
  auto take = [&](size_t nbytes) -> void* {
    void* p = base + off;
    off += (nbytes + 255) & ~(size_t)255;
    return p;
  };
  unsigned short* x_l = (unsigned short*)take((size_t)NTOT * HD * sizeof(unsigned short)); // 51.2 MB
  unsigned short* x_r = (unsigned short*)take((size_t)NTOT * HD * sizeof(unsigned short)); // 51.2 MB
  unsigned short* e_rel = (unsigned short*)take((size_t)(RCOUNT + 1) * HD * sizeof(unsigned short));
  unsigned short* Wbf = (unsigned short*)take((size_t)512 * D * sizeof(unsigned short));   // 128 KB
  int* counts = (int*)take((size_t)N_ENT * sizeof(int));
  int* offsets = (int*)take((size_t)(N_ENT + 1) * sizeof(int));
  int* cursor = (int*)take((size_t)N_ENT * sizeof(int));
  int* bsum = (int*)take(512 * sizeof(int));
  int* bpre = (int*)take(512 * sizeof(int));
  unsigned int* sorted = (unsigned int*)take((size_t)ETOT * sizeof(unsigned int));         // 2 MB

  k_wcast<<<dim3(64), dim3(256), 0, stream>>>(W_l, W_r, Wbf);
  k_rel<<<dim3(RCOUNT + 1), dim3(256), 0, stream>>>(relations, W_ea, W_le, b_le, e_rel, out_edge);
  k_gemm_mfma<<<dim3((NTOT + 63) / 64), dim3(256), 0, stream>>>(entities, queries, Wbf, b_l, b_r, x_l, x_r);
  k_zero<<<dim3((N_ENT + 255) / 256), dim3(256), 0, stream>>>(counts);
  k_hist<<<dim3((ETOT + 255) / 256), dim3(256), 0, stream>>>(edge_index, counts);
  k_scan1<<<dim3(SCAN_NB), dim3(256), 0, stream>>>(counts, bsum);
  k_scan2<<<dim3(1), dim3(512), 0, stream>>>(bsum, bpre);
  k_scan3<<<dim3(SCAN_NB), dim3(256), 0, stream>>>(counts, bpre, offsets, cursor);
  k_scatter<<<dim3((ETOT + 255) / 256), dim3(256), 0, stream>>>(edge_index, relation_index, batch, cursor, sorted);
  k_edge<<<dim3(N_ENT / 4), dim3(256), 0, stream>>>(x_l, x_r, e_rel, offsets, sorted, att, bias, out_node);
}